// Round 1
// baseline (101.455 us; speedup 1.0000x reference)
//
#include <hip/hip_runtime.h>

#define E_ 8
#define R_ 64
#define D_ 2048
#define BS_ 16384
#define SEG 64                               // int offset of per-expert segment lists
#define WS_ABF_OFF (1ull<<20)                // bf16 A (2MB) then B (2MB) at 1 MB
#define WS_NEED_FULL (WS_ABF_OFF + 4ull*1024*1024)

typedef __attribute__((ext_vector_type(8))) short short8;
typedef __attribute__((ext_vector_type(4))) short short4v;
typedef __attribute__((ext_vector_type(4))) float f32x4;

__device__ __forceinline__ unsigned short f2bf(float f){
  unsigned u = __float_as_uint(f);
  u += 0x7fffu + ((u >> 16) & 1u);           // RNE
  return (unsigned short)(u >> 16);
}
__device__ __forceinline__ short8 pack8(f32x4 a, f32x4 b){
  short8 r;
  r[0]=(short)f2bf(a[0]); r[1]=(short)f2bf(a[1]); r[2]=(short)f2bf(a[2]); r[3]=(short)f2bf(a[3]);
  r[4]=(short)f2bf(b[0]); r[5]=(short)f2bf(b[1]); r[6]=(short)f2bf(b[2]); r[7]=(short)f2bf(b[3]);
  return r;
}
// async global->LDS DMA, 16B/lane. LDS dest = wave-uniform base + lane*16
// (linear); global src is PER-LANE (swizzle folded there). Counts in vmcnt.
__device__ __forceinline__ void gload16(const void* g, void* l){
  __builtin_amdgcn_global_load_lds(
      (const __attribute__((address_space(1))) void*)g,
      (__attribute__((address_space(3))) void*)l, 16, 0, 0);
}

// ---- prologue: scatter (blocks 0..63) + A,B fp32->bf16 conv (2048 blocks) ----
// ws ints: [0..8) cursors (end = counts) | [SEG + e*BS_ ...) token lists
__global__ void scatter_conv(const int* __restrict__ tidx, int* __restrict__ ws,
                             const float* __restrict__ Am, const float* __restrict__ Bm,
                             unsigned short* __restrict__ Abf){
  if (blockIdx.x >= 64){
    const int i = (blockIdx.x - 64)*256 + threadIdx.x;     // 4 elems each, 2M total
    const f32x4 v = (i < 262144) ? *(const f32x4*)(Am + (size_t)i*4)
                                 : *(const f32x4*)(Bm + (size_t)(i - 262144)*4);
    short4v a;
    a[0]=(short)f2bf(v[0]); a[1]=(short)f2bf(v[1]); a[2]=(short)f2bf(v[2]); a[3]=(short)f2bf(v[3]);
    *(short4v*)(Abf + (size_t)i*4) = a;                    // Bbf contiguous after Abf
    return;
  }
  __shared__ int lh[E_], lbase[E_], lrank[E_];
  const int t = threadIdx.x;
  if (t < E_){ lh[t] = 0; lrank[t] = 0; }
  __syncthreads();
  const int tok = blockIdx.x*256 + t;
  const int e = tidx[tok];
  atomicAdd(&lh[e], 1);
  __syncthreads();
  if (t < E_) lbase[t] = atomicAdd(&ws[t], lh[t]);   // device-scope
  __syncthreads();
  const int r = atomicAdd(&lrank[e], 1);
  ws[SEG + e*BS_ + lbase[e] + r] = tok;
}

// ---------------- Fused: out[tok] = B_e (A_e x[tok]) ----------------
// vs previous version: BOTH phases are now double-buffered with counted
// s_waitcnt vmcnt(8) + raw s_barrier (T3/T4). Each wave issues exactly 8
// global_load_lds per chunk/tile; vmcnt retires IN ORDER, so after issuing
// the next 8, vmcnt(8) proves the previous chunk landed. Steady state never
// drains vmcnt(0); masked global stores in phase 2 are older than the newest
// 8 loads so vmcnt(8) stays exact (last tile uses vmcnt(0)).
// LDS: ph1 x-dbuf 32K | A-dbuf 32K | H 4K = 68K; ph2 reuses [0,64K) as B-dbuf.
// 2 blocks/CU — unchanged (512 active blocks = 2/CU residency anyway).
__global__ __launch_bounds__(256) void fused(
    const float* __restrict__ x, const unsigned short* __restrict__ Abf,
    const int* __restrict__ ws, float* __restrict__ out)
{
  const int e    = blockIdx.x & 7;
  const int tile = blockIdx.x >> 3;
  const int cnt  = ws[e];
  const int start = tile * 32;
  if (start >= cnt) return;
  const int valid = (cnt - start < 32) ? (cnt - start) : 32;
  const int* seg = ws + SEG + e*BS_;

  __shared__ int tokIds[32];
  __shared__ __align__(16) char smem[69632];   // x0|x1|A0|A1|H ; ph2: B0|B1|H

  const int tid = threadIdx.x;
  if (tid < 32) tokIds[tid] = seg[start + (tid < valid ? tid : valid-1)];
  __syncthreads();

  const int lane = tid & 63, w = tid >> 6;     // 4 waves
  // ---- phase-1 staging sources (per-lane, swizzle pre-folded) ----
  const char* xsrc[4]; const char* asrc[4];
  #pragma unroll
  for (int i = 0; i < 4; ++i){
    const int gi = w*4 + i;
    const int xrow = gi*2 + (lane >> 5);               // 2 rows per 1KB instr
    xsrc[i] = (const char*)(x + (size_t)tokIds[xrow]*D_)
              + (((lane & 31)*16) ^ ((xrow & 7) << 4));
    const int arow = gi*4 + (lane >> 4);               // 4 rows per 1KB instr
    asrc[i] = (const char*)(Abf + ((size_t)e*R_ + arow)*D_)
              + (((lane & 15)*16) ^ ((arow & 7) << 4));
  }
  char* const pH = smem + 65536;                       // 4 KB

  const int llo = lane & 15, lhi = lane >> 4;
  const int tw = w & 1, rw = w >> 1;
  const int xrow_c = tw*16 + llo;            // 0..31
  const int arow0  = rw*32 + llo;            // and +16
  const int sw     = (llo & 7) << 4;         // == (xrow_c&7)<<4 == (arow0&7)<<4
  f32x4 acc0={0.f,0.f,0.f,0.f}, acc1={0.f,0.f,0.f,0.f};

  // 8 gload16/wave per chunk: [0,16K)/[16K,32K) = x bufs, [32K,48K)/[48K,64K) = A bufs
  auto STAGE = [&](int c, int buf){
    char* xd = smem + buf*16384;
    char* ad = smem + 32768 + buf*16384;
    #pragma unroll
    for (int i = 0; i < 4; ++i){
      gload16(xsrc[i] + c*512, xd + (w*4+i)*1024);
      gload16(asrc[i] + c*256, ad + (w*4+i)*1024);
    }
  };
  auto COMPUTE = [&](int buf){
    const char* xd = smem + buf*16384;
    const char* ad = smem + 32768 + buf*16384;
    #pragma unroll
    for (int kk = 0; kk < 4; ++kk){
      const f32x4 v0 = *(const f32x4*)(xd + xrow_c*512 + ((kk*128 + lhi*32) ^ sw));
      const f32x4 v1 = *(const f32x4*)(xd + xrow_c*512 + ((kk*128 + lhi*32 + 16) ^ sw));
      const short8 af = pack8(v0, v1);
      const short8 b0 = *(const short8*)(ad + arow0*256 + ((kk*64 + lhi*16) ^ sw));
      const short8 b1 = *(const short8*)(ad + (arow0+16)*256 + ((kk*64 + lhi*16) ^ sw));
      acc0 = __builtin_amdgcn_mfma_f32_16x16x32_bf16(af, b0, acc0, 0,0,0);
      acc1 = __builtin_amdgcn_mfma_f32_16x16x32_bf16(af, b1, acc1, 0,0,0);
    }
  };
  // one pipelined step: issue chunk c+1 into buf^1, prove chunk c landed
  // (vmcnt(8): the 8 just-issued are the only newer ops), barrier, compute
  // on buf, then barrier before anyone overwrites buf (next step's STAGE).
  auto PSTEP = [&](int c, int buf){
    STAGE(c+1, buf^1);
    asm volatile("s_waitcnt vmcnt(8)" ::: "memory");
    __builtin_amdgcn_s_barrier();
    asm volatile("" ::: "memory");
    COMPUTE(buf);
    __builtin_amdgcn_sched_barrier(0);       // rule 18: pin MFMAs above barrier
    __builtin_amdgcn_s_barrier();
    asm volatile("" ::: "memory");
  };

  STAGE(0, 0);
  #pragma unroll 1
  for (int c2 = 0; c2 < 7; ++c2){
    PSTEP(c2*2,     0);
    PSTEP(c2*2 + 1, 1);
  }
  PSTEP(14, 0);
  // final chunk 15: nothing left to issue -> exact drain of own 8 loads
  asm volatile("s_waitcnt vmcnt(0)" ::: "memory");
  __builtin_amdgcn_s_barrier();
  asm volatile("" ::: "memory");
  COMPUTE(1);
  __builtin_amdgcn_sched_barrier(0);
  __builtin_amdgcn_s_barrier();              // all x/A reads done
  asm volatile("" ::: "memory");

  // ---- phase 2 setup: prefetch B tile 0 under the H round-trip ----
  const unsigned short* Bbf = Abf + E_*R_*D_;
  const char* bsrc = (const char*)Bbf + (size_t)e*D_*R_*2
                     + (size_t)(w*64 + (lane >> 3))*128
                     + (((lane & 7)*16) ^ (((lane >> 3) & 7) << 4));
  auto STAGE_B = [&](int cg, int buf){      // 8 gload16/wave, 32KB tile
    char* pb = smem + buf*32768;
    #pragma unroll
    for (int i2 = 0; i2 < 8; ++i2)
      gload16(bsrc + cg*32768 + i2*1024, pb + (w*8+i2)*1024);
  };
  STAGE_B(0, 0);                            // into [0,32K) — x bufs, now dead

  // ---- H -> LDS (bf16, swizzled). C/D layout: row=(lane>>4)*4+i, col=llo ----
  #pragma unroll
  for (int i = 0; i < 4; ++i){
    const int hr = tw*16 + lhi*4 + i;
    const int hsw = (hr & 7) << 4;
    *(unsigned short*)(pH + ((hr*128 + (rw*32+llo)*2)    ^ hsw)) = f2bf(acc0[i]);
    *(unsigned short*)(pH + ((hr*128 + (rw*32+16+llo)*2) ^ hsw)) = f2bf(acc1[i]);
  }
  asm volatile("s_waitcnt lgkmcnt(0)" ::: "memory");   // ds_writes only; B DMA stays in flight
  __builtin_amdgcn_s_barrier();
  asm volatile("" ::: "memory");

  short8 aH[2][2];
  #pragma unroll
  for (int g = 0; g < 2; ++g){
    const int r_ = g*16 + llo;               // (r_&7) == (llo&7)
    aH[g][0] = *(const short8*)(pH + ((r_*128 + lhi*16) ^ sw));
    aH[g][1] = *(const short8*)(pH + ((r_*128 + 64 + lhi*16) ^ sw));
  }

  unsigned vmask = 0;
  int rowOff[2][4];
  #pragma unroll
  for (int g = 0; g < 2; ++g){
    #pragma unroll
    for (int i = 0; i < 4; ++i){
      const int r_ = g*16 + lhi*4 + i;
      if (r_ < valid) vmask |= 1u << (g*4 + i);
      rowOff[g][i] = tokIds[r_ < valid ? r_ : 0]*D_ + llo;
    }
  }

  // ---- phase 2 pipelined: per tile {issue next, vmcnt(8), barrier, 4nt x 4 MFMA
  // + masked NT stores, barrier}. Stores are older than the 8 newest loads, so
  // vmcnt(8) retires them too; last tile drains fully.
  auto BSTEP = [&](int cg, int buf, bool last){
    if (!last){
      STAGE_B(cg+1, buf^1);
      asm volatile("s_waitcnt vmcnt(8)" ::: "memory");
    } else {
      asm volatile("s_waitcnt vmcnt(0)" ::: "memory");
    }
    __builtin_amdgcn_s_barrier();
    asm volatile("" ::: "memory");
    const char* pb = smem + buf*32768;
    #pragma unroll
    for (int nt = 0; nt < 4; ++nt){
      const int rowL = w*64 + nt*16 + llo;   // (rowL&7) == (llo&7)
      const short8 b0 = *(const short8*)(pb + ((rowL*128 + lhi*16) ^ sw));
      const short8 b1 = *(const short8*)(pb + ((rowL*128 + 64 + lhi*16) ^ sw));
      f32x4 o0 = {0.f,0.f,0.f,0.f}, o1 = {0.f,0.f,0.f,0.f};
      o0 = __builtin_amdgcn_mfma_f32_16x16x32_bf16(aH[0][0], b0, o0, 0,0,0);
      o0 = __builtin_amdgcn_mfma_f32_16x16x32_bf16(aH[0][1], b1, o0, 0,0,0);
      o1 = __builtin_amdgcn_mfma_f32_16x16x32_bf16(aH[1][0], b0, o1, 0,0,0);
      o1 = __builtin_amdgcn_mfma_f32_16x16x32_bf16(aH[1][1], b1, o1, 0,0,0);
      const int col = cg*256 + w*64 + nt*16;
      #pragma unroll
      for (int i = 0; i < 4; ++i){
        if (vmask & (1u <<  i))    __builtin_nontemporal_store(o0[i], &out[rowOff[0][i] + col]);
        if (vmask & (1u << (4+i))) __builtin_nontemporal_store(o1[i], &out[rowOff[1][i] + col]);
      }
    }
    if (!last){
      __builtin_amdgcn_sched_barrier(0);
      __builtin_amdgcn_s_barrier();          // reads done before next DMA lands
      asm volatile("" ::: "memory");
    }
  };
  BSTEP(0,0,false); BSTEP(1,1,false); BSTEP(2,0,false); BSTEP(3,1,false);
  BSTEP(4,0,false); BSTEP(5,1,false); BSTEP(6,0,false); BSTEP(7,1,true);
}

// ---------------- correctness-only fallback (tiny ws): exact fp32 ----------------
__global__ __launch_bounds__(256) void naive_kernel(
    const float* __restrict__ x, const float* __restrict__ Am,
    const float* __restrict__ Bm, const int* __restrict__ tidx,
    float* __restrict__ out)
{
  const int tok = blockIdx.x;
  const int e = tidx[tok];
  __shared__ float xs[D_];
  __shared__ float h[R_];
  const int tid = threadIdx.x;
  for (int i = tid; i < D_; i += 256) xs[i] = x[(size_t)tok*D_ + i];
  __syncthreads();
  if (tid < R_){
    float s = 0.f;
    const float* ar = Am + ((size_t)e*R_ + tid)*D_;
    for (int d = 0; d < D_; ++d) s += xs[d]*ar[d];
    h[tid] = s;
  }
  __syncthreads();
  for (int c = tid; c < D_; c += 256){
    float s = 0.f;
    const float* br = Bm + ((size_t)e*D_ + c)*R_;
    #pragma unroll
    for (int r = 0; r < R_; ++r) s += h[r]*br[r];
    out[(size_t)tok*D_ + c] = s;
  }
}

extern "C" void kernel_launch(void* const* d_in, const int* in_sizes, int n_in,
                              void* d_out, int out_size, void* d_ws, size_t ws_size,
                              hipStream_t stream){
  const float* x    = (const float*)d_in[0];
  const float* Am   = (const float*)d_in[1];
  const float* Bm   = (const float*)d_in[2];
  const int*   tidx = (const int*)d_in[3];
  float* out = (float*)d_out;
  int*   ws  = (int*)d_ws;
  unsigned short* Abf = (unsigned short*)((char*)d_ws + WS_ABF_OFF);

  if (ws_size >= WS_NEED_FULL){
    hipMemsetAsync(d_ws, 0, 32, stream);                    // zero 8 cursors
    scatter_conv<<<64 + 2048, 256, 0, stream>>>(tidx, ws, Am, Bm, Abf);
    fused<<<8*(BS_/32), 256, 0, stream>>>(x, Abf, ws, out);
  } else {
    naive_kernel<<<BS_, 256, 0, stream>>>(x, Am, Bm, tidx, out);
  }
}

// Round 2
// 99.804 us; speedup vs baseline: 1.0165x; 1.0165x over previous
//
#include <hip/hip_runtime.h>

#define E_ 8
#define R_ 64
#define D_ 2048
#define BS_ 16384
#define SEG 64                               // int offset of per-expert segment lists
#define WS_ABF_OFF (1ull<<20)                // bf16 A (2MB) then B (2MB) at 1 MB
#define WS_NEED_FULL (WS_ABF_OFF + 4ull*1024*1024)

typedef __attribute__((ext_vector_type(8))) short short8;
typedef __attribute__((ext_vector_type(4))) short short4v;
typedef __attribute__((ext_vector_type(4))) float f32x4;

__device__ __forceinline__ unsigned short f2bf(float f){
  unsigned u = __float_as_uint(f);
  u += 0x7fffu + ((u >> 16) & 1u);           // RNE
  return (unsigned short)(u >> 16);
}
__device__ __forceinline__ short8 pack8(f32x4 a, f32x4 b){
  short8 r;
  r[0]=(short)f2bf(a[0]); r[1]=(short)f2bf(a[1]); r[2]=(short)f2bf(a[2]); r[3]=(short)f2bf(a[3]);
  r[4]=(short)f2bf(b[0]); r[5]=(short)f2bf(b[1]); r[6]=(short)f2bf(b[2]); r[7]=(short)f2bf(b[3]);
  return r;
}
// async global->LDS DMA, 16B/lane. LDS dest = wave-uniform base + lane*16
// (linear); global src is PER-LANE (swizzle folded there). Counts in vmcnt.
__device__ __forceinline__ void gload16(const void* g, void* l){
  __builtin_amdgcn_global_load_lds(
      (const __attribute__((address_space(1))) void*)g,
      (__attribute__((address_space(3))) void*)l, 16, 0, 0);
}

// ---- prologue: scatter (blocks 0..63) + A,B fp32->bf16 conv (2048 blocks) ----
// ws ints: [0..8) cursors (end = counts) | [SEG + e*BS_ ...) token lists
__global__ void scatter_conv(const int* __restrict__ tidx, int* __restrict__ ws,
                             const float* __restrict__ Am, const float* __restrict__ Bm,
                             unsigned short* __restrict__ Abf){
  if (blockIdx.x >= 64){
    const int i = (blockIdx.x - 64)*256 + threadIdx.x;     // 4 elems each, 2M total
    const f32x4 v = (i < 262144) ? *(const f32x4*)(Am + (size_t)i*4)
                                 : *(const f32x4*)(Bm + (size_t)(i - 262144)*4);
    short4v a;
    a[0]=(short)f2bf(v[0]); a[1]=(short)f2bf(v[1]); a[2]=(short)f2bf(v[2]); a[3]=(short)f2bf(v[3]);
    *(short4v*)(Abf + (size_t)i*4) = a;                    // Bbf contiguous after Abf
    return;
  }
  __shared__ int lh[E_], lbase[E_], lrank[E_];
  const int t = threadIdx.x;
  if (t < E_){ lh[t] = 0; lrank[t] = 0; }
  __syncthreads();
  const int tok = blockIdx.x*256 + t;
  const int e = tidx[tok];
  atomicAdd(&lh[e], 1);
  __syncthreads();
  if (t < E_) lbase[t] = atomicAdd(&ws[t], lh[t]);   // device-scope
  __syncthreads();
  const int r = atomicAdd(&lrank[e], 1);
  ws[SEG + e*BS_ + lbase[e] + r] = tok;
}

// ---------------- Fused: out[tok] = B_e (A_e x[tok]) ----------------
// Double-buffered both phases with counted s_waitcnt vmcnt(8) + raw s_barrier
// (T3/T4). vs Round-1: ALL sched_barrier(0) pins removed (m141/rule-18: they
// defeat the compiler scheduler and are only needed for inline-asm ds_reads;
// ours are compiler-emitted). Phase boundary = {STAGE next; vmcnt(8); barrier;
// COMPUTE (setprio around MFMA); lgkmcnt(0); barrier}. The two memory-clobbered
// waitcnt asms are the only fences: DMA issue can't hoist above lgkmcnt(0),
// ds_reads can't sink below it -> buffer-overwrite safety holds.
// LDS: ph1 x-dbuf 32K | A-dbuf 32K | H 4K = 68K; ph2 reuses [0,64K) as B-dbuf.
__global__ __launch_bounds__(256) void fused(
    const float* __restrict__ x, const unsigned short* __restrict__ Abf,
    const int* __restrict__ ws, float* __restrict__ out)
{
  const int e    = blockIdx.x & 7;
  const int tile = blockIdx.x >> 3;
  const int cnt  = ws[e];
  const int start = tile * 32;
  if (start >= cnt) return;
  const int valid = (cnt - start < 32) ? (cnt - start) : 32;
  const int* seg = ws + SEG + e*BS_;

  __shared__ int tokIds[32];
  __shared__ __align__(16) char smem[69632];   // x0|x1|A0|A1|H ; ph2: B0|B1|H

  const int tid = threadIdx.x;
  if (tid < 32) tokIds[tid] = seg[start + (tid < valid ? tid : valid-1)];
  __syncthreads();

  const int lane = tid & 63, w = tid >> 6;     // 4 waves
  // ---- phase-1 staging sources (per-lane, swizzle pre-folded) ----
  const char* xsrc[4]; const char* asrc[4];
  #pragma unroll
  for (int i = 0; i < 4; ++i){
    const int gi = w*4 + i;
    const int xrow = gi*2 + (lane >> 5);               // 2 rows per 1KB instr
    xsrc[i] = (const char*)(x + (size_t)tokIds[xrow]*D_)
              + (((lane & 31)*16) ^ ((xrow & 7) << 4));
    const int arow = gi*4 + (lane >> 4);               // 4 rows per 1KB instr
    asrc[i] = (const char*)(Abf + ((size_t)e*R_ + arow)*D_)
              + (((lane & 15)*16) ^ ((arow & 7) << 4));
  }
  char* const pH = smem + 65536;                       // 4 KB

  const int llo = lane & 15, lhi = lane >> 4;
  const int tw = w & 1, rw = w >> 1;
  const int xrow_c = tw*16 + llo;            // 0..31
  const int arow0  = rw*32 + llo;            // and +16
  const int sw     = (llo & 7) << 4;         // == (xrow_c&7)<<4 == (arow0&7)<<4
  f32x4 acc0={0.f,0.f,0.f,0.f}, acc1={0.f,0.f,0.f,0.f};

  // 8 gload16/wave per chunk: [0,16K)/[16K,32K) = x bufs, [32K,48K)/[48K,64K) = A bufs
  auto STAGE = [&](int c, int buf){
    char* xd = smem + buf*16384;
    char* ad = smem + 32768 + buf*16384;
    #pragma unroll
    for (int i = 0; i < 4; ++i){
      gload16(xsrc[i] + c*512, xd + (w*4+i)*1024);
      gload16(asrc[i] + c*256, ad + (w*4+i)*1024);
    }
  };
  auto COMPUTE = [&](int buf){
    const char* xd = smem + buf*16384;
    const char* ad = smem + 32768 + buf*16384;
    f32x4 v0[4], v1[4]; short8 b0[4], b1[4];
    #pragma unroll
    for (int kk = 0; kk < 4; ++kk){
      v0[kk] = *(const f32x4*)(xd + xrow_c*512 + ((kk*128 + lhi*32) ^ sw));
      v1[kk] = *(const f32x4*)(xd + xrow_c*512 + ((kk*128 + lhi*32 + 16) ^ sw));
      b0[kk] = *(const short8*)(ad + arow0*256 + ((kk*64 + lhi*16) ^ sw));
      b1[kk] = *(const short8*)(ad + (arow0+16)*256 + ((kk*64 + lhi*16) ^ sw));
    }
    __builtin_amdgcn_s_setprio(1);
    #pragma unroll
    for (int kk = 0; kk < 4; ++kk){
      const short8 af = pack8(v0[kk], v1[kk]);
      acc0 = __builtin_amdgcn_mfma_f32_16x16x32_bf16(af, b0[kk], acc0, 0,0,0);
      acc1 = __builtin_amdgcn_mfma_f32_16x16x32_bf16(af, b1[kk], acc1, 0,0,0);
    }
    __builtin_amdgcn_s_setprio(0);
  };
  // one pipelined step: issue chunk c+1 into buf^1, prove chunk c landed
  // (vmcnt(8): the 8 just-issued are the only newer ops), barrier, compute
  // on buf, lgkmcnt(0) (ds_reads done), barrier (buf safe to overwrite).
  auto PSTEP = [&](int c, int buf){
    STAGE(c+1, buf^1);
    asm volatile("s_waitcnt vmcnt(8)" ::: "memory");
    __builtin_amdgcn_s_barrier();
    COMPUTE(buf);
    asm volatile("s_waitcnt lgkmcnt(0)" ::: "memory");
    __builtin_amdgcn_s_barrier();
  };

  STAGE(0, 0);
  #pragma unroll 1
  for (int c2 = 0; c2 < 7; ++c2){
    PSTEP(c2*2,     0);
    PSTEP(c2*2 + 1, 1);
  }
  PSTEP(14, 0);
  // final chunk 15: nothing left to issue -> exact drain of own 8 loads
  asm volatile("s_waitcnt vmcnt(0)" ::: "memory");
  __builtin_amdgcn_s_barrier();
  COMPUTE(1);
  asm volatile("s_waitcnt lgkmcnt(0)" ::: "memory");
  __builtin_amdgcn_s_barrier();              // all x/A reads done

  // ---- phase 2 setup: prefetch B tile 0 under the H round-trip ----
  const unsigned short* Bbf = Abf + E_*R_*D_;
  const char* bsrc = (const char*)Bbf + (size_t)e*D_*R_*2
                     + (size_t)(w*64 + (lane >> 3))*128
                     + (((lane & 7)*16) ^ (((lane >> 3) & 7) << 4));
  auto STAGE_B = [&](int cg, int buf){      // 8 gload16/wave, 32KB tile
    char* pb = smem + buf*32768;
    #pragma unroll
    for (int i2 = 0; i2 < 8; ++i2)
      gload16(bsrc + cg*32768 + i2*1024, pb + (w*8+i2)*1024);
  };
  STAGE_B(0, 0);                            // into [0,32K) — x bufs, now dead

  // ---- H -> LDS (bf16, swizzled). C/D layout: row=(lane>>4)*4+i, col=llo ----
  #pragma unroll
  for (int i = 0; i < 4; ++i){
    const int hr = tw*16 + lhi*4 + i;
    const int hsw = (hr & 7) << 4;
    *(unsigned short*)(pH + ((hr*128 + (rw*32+llo)*2)    ^ hsw)) = f2bf(acc0[i]);
    *(unsigned short*)(pH + ((hr*128 + (rw*32+16+llo)*2) ^ hsw)) = f2bf(acc1[i]);
  }
  asm volatile("s_waitcnt lgkmcnt(0)" ::: "memory");   // ds_writes only; B DMA in flight
  __builtin_amdgcn_s_barrier();

  short8 aH[2][2];
  #pragma unroll
  for (int g = 0; g < 2; ++g){
    const int r_ = g*16 + llo;               // (r_&7) == (llo&7)
    aH[g][0] = *(const short8*)(pH + ((r_*128 + lhi*16) ^ sw));
    aH[g][1] = *(const short8*)(pH + ((r_*128 + 64 + lhi*16) ^ sw));
  }

  unsigned vmask = 0;
  int rowOff[2][4];
  #pragma unroll
  for (int g = 0; g < 2; ++g){
    #pragma unroll
    for (int i = 0; i < 4; ++i){
      const int r_ = g*16 + lhi*4 + i;
      if (r_ < valid) vmask |= 1u << (g*4 + i);
      rowOff[g][i] = tokIds[r_ < valid ? r_ : 0]*D_ + llo;
    }
  }

  // ---- phase 2 pipelined: {issue next; vmcnt(8); barrier; 4nt x 4 MFMA +
  // masked NT stores; lgkmcnt(0); barrier}. Stores are older than the 8
  // newest loads, so vmcnt(8) retires them too; last tile drains fully.
  auto BSTEP = [&](int cg, int buf, bool last){
    if (!last){
      STAGE_B(cg+1, buf^1);
      asm volatile("s_waitcnt vmcnt(8)" ::: "memory");
    } else {
      asm volatile("s_waitcnt vmcnt(0)" ::: "memory");
    }
    __builtin_amdgcn_s_barrier();
    const char* pb = smem + buf*32768;
    #pragma unroll
    for (int nt = 0; nt < 4; ++nt){
      const int rowL = w*64 + nt*16 + llo;   // (rowL&7) == (llo&7)
      const short8 b0 = *(const short8*)(pb + ((rowL*128 + lhi*16) ^ sw));
      const short8 b1 = *(const short8*)(pb + ((rowL*128 + 64 + lhi*16) ^ sw));
      f32x4 o0 = {0.f,0.f,0.f,0.f}, o1 = {0.f,0.f,0.f,0.f};
      __builtin_amdgcn_s_setprio(1);
      o0 = __builtin_amdgcn_mfma_f32_16x16x32_bf16(aH[0][0], b0, o0, 0,0,0);
      o0 = __builtin_amdgcn_mfma_f32_16x16x32_bf16(aH[0][1], b1, o0, 0,0,0);
      o1 = __builtin_amdgcn_mfma_f32_16x16x32_bf16(aH[1][0], b0, o1, 0,0,0);
      o1 = __builtin_amdgcn_mfma_f32_16x16x32_bf16(aH[1][1], b1, o1, 0,0,0);
      __builtin_amdgcn_s_setprio(0);
      const int col = cg*256 + w*64 + nt*16;
      #pragma unroll
      for (int i = 0; i < 4; ++i){
        if (vmask & (1u <<  i))    __builtin_nontemporal_store(o0[i], &out[rowOff[0][i] + col]);
        if (vmask & (1u << (4+i))) __builtin_nontemporal_store(o1[i], &out[rowOff[1][i] + col]);
      }
    }
    if (!last){
      asm volatile("s_waitcnt lgkmcnt(0)" ::: "memory");
      __builtin_amdgcn_s_barrier();          // reads done before next DMA lands
    }
  };
  BSTEP(0,0,false); BSTEP(1,1,false); BSTEP(2,0,false); BSTEP(3,1,false);
  BSTEP(4,0,false); BSTEP(5,1,false); BSTEP(6,0,false); BSTEP(7,1,true);
}

// ---------------- correctness-only fallback (tiny ws): exact fp32 ----------------
__global__ __launch_bounds__(256) void naive_kernel(
    const float* __restrict__ x, const float* __restrict__ Am,
    const float* __restrict__ Bm, const int* __restrict__ tidx,
    float* __restrict__ out)
{
  const int tok = blockIdx.x;
  const int e = tidx[tok];
  __shared__ float xs[D_];
  __shared__ float h[R_];
  const int tid = threadIdx.x;
  for (int i = tid; i < D_; i += 256) xs[i] = x[(size_t)tok*D_ + i];
  __syncthreads();
  if (tid < R_){
    float s = 0.f;
    const float* ar = Am + ((size_t)e*R_ + tid)*D_;
    for (int d = 0; d < D_; ++d) s += xs[d]*ar[d];
    h[tid] = s;
  }
  __syncthreads();
  for (int c = tid; c < D_; c += 256){
    float s = 0.f;
    const float* br = Bm + ((size_t)e*D_ + c)*R_;
    #pragma unroll
    for (int r = 0; r < R_; ++r) s += h[r]*br[r];
    out[(size_t)tok*D_ + c] = s;
  }
}

extern "C" void kernel_launch(void* const* d_in, const int* in_sizes, int n_in,
                              void* d_out, int out_size, void* d_ws, size_t ws_size,
                              hipStream_t stream){
  const float* x    = (const float*)d_in[0];
  const float* Am   = (const float*)d_in[1];
  const float* Bm   = (const float*)d_in[2];
  const int*   tidx = (const int*)d_in[3];
  float* out = (float*)d_out;
  int*   ws  = (int*)d_ws;
  unsigned short* Abf = (unsigned short*)((char*)d_ws + WS_ABF_OFF);

  if (ws_size >= WS_NEED_FULL){
    hipMemsetAsync(d_ws, 0, 32, stream);                    // zero 8 cursors
    scatter_conv<<<64 + 2048, 256, 0, stream>>>(tidx, ws, Am, Bm, Abf);
    fused<<<8*(BS_/32), 256, 0, stream>>>(x, Abf, ws, out);
  } else {
    naive_kernel<<<BS_, 256, 0, stream>>>(x, Am, Bm, tidx, out);
  }
}

// Round 4
// 87.450 us; speedup vs baseline: 1.1602x; 1.1413x over previous
//
#include <hip/hip_runtime.h>

#define E_ 8
#define R_ 64
#define D_ 2048
#define BS_ 16384
#define SEG 64                               // int offset of per-expert segment lists
#define WS_ABF_OFF (1ull<<20)                // bf16 A (2MB) then B (2MB) at 1 MB
#define WS_HP_OFF  (WS_ABF_OFF + 4ull*1024*1024)   // fp32 H K-partials, 16 MB
#define WS_NEED_FULL (WS_HP_OFF + 16ull*1024*1024)
#define NTILE 128                            // tiles/expert: covers cnt<=4096 (48 sigma)
#define KSLICE_F (BS_*R_)                    // floats per ks slice of Hp

typedef __attribute__((ext_vector_type(8))) short short8;
typedef __attribute__((ext_vector_type(4))) short short4v;
typedef __attribute__((ext_vector_type(4))) float f32x4;

__device__ __forceinline__ unsigned short f2bf(float f){
  unsigned u = __float_as_uint(f);
  u += 0x7fffu + ((u >> 16) & 1u);           // RNE
  return (unsigned short)(u >> 16);
}
__device__ __forceinline__ short8 pack8(f32x4 a, f32x4 b){
  short8 r;
  r[0]=(short)f2bf(a[0]); r[1]=(short)f2bf(a[1]); r[2]=(short)f2bf(a[2]); r[3]=(short)f2bf(a[3]);
  r[4]=(short)f2bf(b[0]); r[5]=(short)f2bf(b[1]); r[6]=(short)f2bf(b[2]); r[7]=(short)f2bf(b[3]);
  return r;
}
// async global->LDS DMA, 16B/lane. LDS dest = wave-uniform base + lane*16
// (linear); global src is PER-LANE (swizzle folded there). Counts in vmcnt;
// __syncthreads()'s implied vmcnt(0) is the completion wait (proven).
__device__ __forceinline__ void gload16(const void* g, void* l){
  __builtin_amdgcn_global_load_lds(
      (const __attribute__((address_space(1))) void*)g,
      (__attribute__((address_space(3))) void*)l, 16, 0, 0);
}

// ---- prologue: scatter (blocks 0..63) + A,B fp32->bf16 conv (2048 blocks) ----
// ws ints: [0..8) cursors (end = counts) | [SEG + e*BS_ ...) token lists
__global__ void scatter_conv(const int* __restrict__ tidx, int* __restrict__ ws,
                             const float* __restrict__ Am, const float* __restrict__ Bm,
                             unsigned short* __restrict__ Abf){
  if (blockIdx.x >= 64){
    const int i = (blockIdx.x - 64)*256 + threadIdx.x;     // 4 elems each, 2M total
    const f32x4 v = (i < 262144) ? *(const f32x4*)(Am + (size_t)i*4)
                                 : *(const f32x4*)(Bm + (size_t)(i - 262144)*4);
    short4v a;
    a[0]=(short)f2bf(v[0]); a[1]=(short)f2bf(v[1]); a[2]=(short)f2bf(v[2]); a[3]=(short)f2bf(v[3]);
    *(short4v*)(Abf + (size_t)i*4) = a;                    // Bbf contiguous after Abf
    return;
  }
  __shared__ int lh[E_], lbase[E_], lrank[E_];
  const int t = threadIdx.x;
  if (t < E_){ lh[t] = 0; lrank[t] = 0; }
  __syncthreads();
  const int tok = blockIdx.x*256 + t;
  const int e = tidx[tok];
  atomicAdd(&lh[e], 1);
  __syncthreads();
  if (t < E_) lbase[t] = atomicAdd(&ws[t], lh[t]);   // device-scope
  __syncthreads();
  const int r = atomicAdd(&lrank[e], 1);
  ws[SEG + e*BS_ + lbase[e] + r] = tok;
}

// ---------------- stage 1 (split-K): Hp[ks][tok] = A_e[:, ks-slice] x[tok, ks-slice] ----
// Proven single-buffered 2-barrier chunk loop, but each block covers only 4 of
// 16 d-chunks (ks = K-slice). ~2052 active blocks (4x TLP), 4x shorter serial
// chain, ZERO extra read traffic (slices partition d). fp32 partials are
// TOKEN-indexed (Hp + ks*BS_*R_ + tok*R_) so coverage is tile-count-independent.
// Clamped duplicate rows write identical values to the same address (benign).
__global__ __launch_bounds__(256) void stage1(
    const float* __restrict__ x, const unsigned short* __restrict__ Abf,
    const int* __restrict__ ws, float* __restrict__ Hp)
{
  const int e    = blockIdx.x & 7;
  const int tile = (blockIdx.x >> 3) & (NTILE-1);
  const int ks   = blockIdx.x >> 10;           // 0..3, 512 d-cols each
  const int cnt  = ws[e];
  const int start = tile * 32;
  if (start >= cnt) return;
  const int valid = (cnt - start < 32) ? (cnt - start) : 32;
  const int* seg = ws + SEG + e*BS_;

  __shared__ int tokIds[32];
  __shared__ __align__(16) char smem[32768];   // x 16K | A 16K (single-buffered)

  const int tid = threadIdx.x;
  if (tid < 32) tokIds[tid] = seg[start + (tid < valid ? tid : valid-1)];
  __syncthreads();

  const int lane = tid & 63, w = tid >> 6;     // 4 waves
  const char* xsrc[4]; const char* asrc[4];
  #pragma unroll
  for (int i = 0; i < 4; ++i){
    const int gi = w*4 + i;
    const int xrow = gi*2 + (lane >> 5);               // 2 rows per 1KB instr
    xsrc[i] = (const char*)(x + (size_t)tokIds[xrow]*D_)
              + (((lane & 31)*16) ^ ((xrow & 7) << 4));
    const int arow = gi*4 + (lane >> 4);               // 4 rows per 1KB instr
    asrc[i] = (const char*)(Abf + ((size_t)e*R_ + arow)*D_)
              + (((lane & 15)*16) ^ ((arow & 7) << 4));
  }
  char* const xdst = smem;
  char* const adst = smem + 16384;

  const int llo = lane & 15, lhi = lane >> 4;
  const int tw = w & 1, rw = w >> 1;
  const int xrow_c = tw*16 + llo;            // 0..31
  const int arow0  = rw*32 + llo;            // and +16
  const int sw     = (llo & 7) << 4;         // == (xrow_c&7)<<4 == (arow0&7)<<4
  f32x4 acc0={0.f,0.f,0.f,0.f}, acc1={0.f,0.f,0.f,0.f};

  const int cbase = ks*4;
  #pragma unroll
  for (int cc = 0; cc < 4; ++cc){
    const int c = cbase + cc;
    #pragma unroll
    for (int i = 0; i < 4; ++i){
      gload16(xsrc[i] + c*512, xdst + (w*4+i)*1024);
      gload16(asrc[i] + c*256, adst + (w*4+i)*1024);
    }
    __syncthreads();                         // chunk landed (implied vmcnt(0))
    #pragma unroll
    for (int kk = 0; kk < 4; ++kk){
      const f32x4 v0 = *(const f32x4*)(xdst + xrow_c*512 + ((kk*128 + lhi*32) ^ sw));
      const f32x4 v1 = *(const f32x4*)(xdst + xrow_c*512 + ((kk*128 + lhi*32 + 16) ^ sw));
      const short8 af = pack8(v0, v1);
      const short8 b0 = *(const short8*)(adst + arow0*256 + ((kk*64 + lhi*16) ^ sw));
      const short8 b1 = *(const short8*)(adst + (arow0+16)*256 + ((kk*64 + lhi*16) ^ sw));
      acc0 = __builtin_amdgcn_mfma_f32_16x16x32_bf16(af, b0, acc0, 0,0,0);
      acc1 = __builtin_amdgcn_mfma_f32_16x16x32_bf16(af, b1, acc1, 0,0,0);
    }
    __syncthreads();                         // reads done before next DMA lands
  }

  // fp32 partials, token-indexed (plain stores -> cached for stage2)
  float* const hks = Hp + (size_t)ks*KSLICE_F;
  #pragma unroll
  for (int i = 0; i < 4; ++i){
    const int hr = tw*16 + lhi*4 + i;        // C/D layout: row=(lane>>4)*4+i
    float* hrow = hks + (size_t)tokIds[hr]*R_;
    hrow[rw*32 + llo]      = acc0[i];
    hrow[rw*32 + 16 + llo] = acc1[i];
  }
}

// ---------------- stage 2 (column-parallel): out[tok, cg] = H B_e[cg]^T ----
// ~4100 active blocks (tile x 8 col-groups of 256), chain length 1: issue
// B-tile DMA, sum the 4 Hp partials (hides DMA latency; token ids read
// directly from seg, no barrier needed), one barrier, 16 MFMA, masked NT
// stores. Frag/swizzle/store code identical to the proven phase 2.
__global__ __launch_bounds__(256) void stage2(
    const unsigned short* __restrict__ Abf, const float* __restrict__ Hp,
    const int* __restrict__ ws, float* __restrict__ out)
{
  const int e    = blockIdx.x & 7;
  const int tile = (blockIdx.x >> 3) & (NTILE-1);
  const int cg   = blockIdx.x >> 10;           // 0..7, 256 out-cols each
  const int cnt  = ws[e];
  const int start = tile * 32;
  if (start >= cnt) return;
  const int valid = (cnt - start < 32) ? (cnt - start) : 32;
  const int* seg = ws + SEG + e*BS_;

  __shared__ int tokIds[32];
  __shared__ __align__(16) char smem[36864];   // B 32K | H 4K

  const int tid = threadIdx.x;
  if (tid < 32) tokIds[tid] = seg[start + (tid < valid ? tid : valid-1)];

  const int lane = tid & 63, w = tid >> 6;
  const int llo = lane & 15, lhi = lane >> 4;
  const int sw  = (llo & 7) << 4;
  char* const pB = smem;
  char* const pH = smem + 32768;

  // issue B-tile DMA first; its latency hides under the Hp partial-sum below
  const unsigned short* Bbf = Abf + E_*R_*D_;
  const char* bsrc = (const char*)Bbf + (size_t)e*D_*R_*2 + (size_t)cg*32768
                     + (size_t)(w*64 + (lane >> 3))*128
                     + (((lane & 7)*16) ^ (((lane >> 3) & 7) << 4));
  #pragma unroll
  for (int i2 = 0; i2 < 8; ++i2)
    gload16(bsrc + i2*1024, pB + (w*8+i2)*1024);

  // sum 4 fp32 K-partials of H (32x64), convert bf16, store swizzled to pH.
  // token id fetched straight from seg (32 distinct, L2-hit) -> no barrier.
  const int hrow = tid >> 3;                   // 0..31
  const int tokH = seg[start + (hrow < valid ? hrow : valid-1)];
  const float* hp = Hp + (size_t)tokH*R_ + (tid & 7)*8;
  f32x4 s0 = {0.f,0.f,0.f,0.f}, s1 = {0.f,0.f,0.f,0.f};
  #pragma unroll
  for (int k2 = 0; k2 < 4; ++k2){
    s0 += *(const f32x4*)(hp + (size_t)k2*KSLICE_F);
    s1 += *(const f32x4*)(hp + (size_t)k2*KSLICE_F + 4);
  }
  const int hc = (tid & 7)*8;                  // col 0,8,..,56
  // 16B-aligned store; XOR of bits 4..6 permutes whole 16B slots -> matches
  // the per-element swizzle (hrow*128 + col*2) ^ ((hrow&7)<<4)
  *(short8*)(pH + ((hrow*128 + hc*2) ^ ((hrow & 7) << 4))) = pack8(s0, s1);
  __syncthreads();     // drains B DMA (implied vmcnt(0)) + pH writes + tokIds

  short8 aH[2][2];
  #pragma unroll
  for (int g = 0; g < 2; ++g){
    const int r_ = g*16 + llo;                 // (r_&7) == (llo&7)
    aH[g][0] = *(const short8*)(pH + ((r_*128 + lhi*16) ^ sw));
    aH[g][1] = *(const short8*)(pH + ((r_*128 + 64 + lhi*16) ^ sw));
  }

  unsigned vmask = 0;
  int rowOff[2][4];
  #pragma unroll
  for (int g = 0; g < 2; ++g){
    #pragma unroll
    for (int i = 0; i < 4; ++i){
      const int r_ = g*16 + lhi*4 + i;
      if (r_ < valid) vmask |= 1u << (g*4 + i);
      rowOff[g][i] = tokIds[r_ < valid ? r_ : 0]*D_ + llo;
    }
  }

  #pragma unroll
  for (int nt = 0; nt < 4; ++nt){
    const int rowL = w*64 + nt*16 + llo;       // (rowL&7) == (llo&7)
    const short8 b0 = *(const short8*)(pB + ((rowL*128 + lhi*16) ^ sw));
    const short8 b1 = *(const short8*)(pB + ((rowL*128 + 64 + lhi*16) ^ sw));
    f32x4 o0 = {0.f,0.f,0.f,0.f}, o1 = {0.f,0.f,0.f,0.f};
    o0 = __builtin_amdgcn_mfma_f32_16x16x32_bf16(aH[0][0], b0, o0, 0,0,0);
    o0 = __builtin_amdgcn_mfma_f32_16x16x32_bf16(aH[0][1], b1, o0, 0,0,0);
    o1 = __builtin_amdgcn_mfma_f32_16x16x32_bf16(aH[1][0], b0, o1, 0,0,0);
    o1 = __builtin_amdgcn_mfma_f32_16x16x32_bf16(aH[1][1], b1, o1, 0,0,0);
    const int col = cg*256 + w*64 + nt*16;
    #pragma unroll
    for (int i = 0; i < 4; ++i){
      if (vmask & (1u <<  i))    __builtin_nontemporal_store(o0[i], &out[rowOff[0][i] + col]);
      if (vmask & (1u << (4+i))) __builtin_nontemporal_store(o1[i], &out[rowOff[1][i] + col]);
    }
  }
}

// ---------------- correctness-only fallback (tiny ws): exact fp32 ----------------
__global__ __launch_bounds__(256) void naive_kernel(
    const float* __restrict__ x, const float* __restrict__ Am,
    const float* __restrict__ Bm, const int* __restrict__ tidx,
    float* __restrict__ out)
{
  const int tok = blockIdx.x;
  const int e = tidx[tok];
  __shared__ float xs[D_];
  __shared__ float h[R_];
  const int tid = threadIdx.x;
  for (int i = tid; i < D_; i += 256) xs[i] = x[(size_t)tok*D_ + i];
  __syncthreads();
  if (tid < R_){
    float s = 0.f;
    const float* ar = Am + ((size_t)e*R_ + tid)*D_;
    for (int d = 0; d < D_; ++d) s += xs[d]*ar[d];
    h[tid] = s;
  }
  __syncthreads();
  for (int c = tid; c < D_; c += 256){
    float s = 0.f;
    const float* br = Bm + ((size_t)e*D_ + c)*R_;
    #pragma unroll
    for (int r = 0; r < R_; ++r) s += h[r]*br[r];
    out[(size_t)tok*D_ + c] = s;
  }
}

extern "C" void kernel_launch(void* const* d_in, const int* in_sizes, int n_in,
                              void* d_out, int out_size, void* d_ws, size_t ws_size,
                              hipStream_t stream){
  const float* x    = (const float*)d_in[0];
  const float* Am   = (const float*)d_in[1];
  const float* Bm   = (const float*)d_in[2];
  const int*   tidx = (const int*)d_in[3];
  float* out = (float*)d_out;
  int*   ws  = (int*)d_ws;
  unsigned short* Abf = (unsigned short*)((char*)d_ws + WS_ABF_OFF);
  float* Hp = (float*)((char*)d_ws + WS_HP_OFF);

  if (ws_size >= WS_NEED_FULL){
    hipMemsetAsync(d_ws, 0, 32, stream);                    // zero 8 cursors
    scatter_conv<<<64 + 2048, 256, 0, stream>>>(tidx, ws, Am, Bm, Abf);
    stage1<<<4*8*NTILE, 256, 0, stream>>>(x, Abf, ws, Hp);   // 4096 blocks, ~2052 active
    stage2<<<8*8*NTILE, 256, 0, stream>>>(Abf, Hp, ws, out); // 8192 blocks, ~4104 active
  } else {
    naive_kernel<<<BS_, 256, 0, stream>>>(x, Am, Bm, tidx, out);
  }
}